// Round 5
// baseline (176.623 us; speedup 1.0000x reference)
//
#include <hip/hip_runtime.h>

// CurvatureLoss: out = sum(|lap(pred) - lap(target)| * mask) / (sum(mask) + 1e-8)
// lap = 3x3 Laplacian, zero ("SAME") padding.  lap(pred)-lap(target) == lap(pred-target).
//
// R4: one WAVE owns a full 1024-wide row span (16 elems/lane = 4 x float4 groups
// of 256 cols). Horizontal neighbors via rotate-shuffles (boundary lane sources
// the adjacent group's register) -> NO divergent edge loads (R1/R3's per-row
// 2-lane scalar loads exposed ~full memory latency every row). Row-boundary
// checks are wave-uniform. Named Row structs only (R2 lesson: arrays -> scratch).
// 4 rows/wave, 4 waves/block -> 1024 blocks, 16 waves/CU, VGPR capped at 128.
// Fused last-block reduction + XCD-chunked swizzle kept from R3 (both correct).

static constexpr int IMG_W = 1024;
static constexpr int IMG_H = 1024;
static constexpr int WROWS = 4;               // rows per wave
static constexpr int NT    = 256;             // 4 waves -> 16 rows per block
static constexpr int NXCD  = 8;

struct Row { float4 a, b, c, d; };            // 4 groups x 4 cols = 16 elems/lane

__device__ __forceinline__ float4 f4z() { return make_float4(0.f,0.f,0.f,0.f); }
__device__ __forceinline__ float4 f4sub(float4 x, float4 y) {
    return make_float4(x.x-y.x, x.y-y.y, x.z-y.z, x.w-y.w);
}

__global__ __launch_bounds__(NT, 4) void curv_kernel(
    const float* __restrict__ pred,
    const float* __restrict__ target,
    const float* __restrict__ mask,
    float* __restrict__ partial,
    unsigned int* __restrict__ counter,
    float* __restrict__ out,
    int H, int nblocks)
{
    const int bid = blockIdx.x;
    const int cpx = nblocks / NXCD;
    const int wid = (bid % NXCD) * cpx + bid / NXCD;   // XCD-chunked swizzle

    const int tid  = threadIdx.x;
    const int lane = tid & 63;
    const int wv   = tid >> 6;
    const int rowsPerBlock = 4 * WROWS;                // 16
    const int bpi  = H / rowsPerBlock;                 // strips per image
    const int img  = wid / bpi;
    const int wy0  = (wid % bpi) * rowsPerBlock + wv * WROWS;
    const size_t imgOff = (size_t)img * H * IMG_W;
    const int xl = lane * 4;

    auto rawRow = [&](const float* __restrict__ p, int y) -> Row {
        Row r;
        if (y < 0 || y >= H) { r.a = r.b = r.c = r.d = f4z(); return r; }  // wave-uniform
        const float* base = p + imgOff + (size_t)y * IMG_W + xl;
        r.a = *reinterpret_cast<const float4*>(base);
        r.b = *reinterpret_cast<const float4*>(base + 256);
        r.c = *reinterpret_cast<const float4*>(base + 512);
        r.d = *reinterpret_cast<const float4*>(base + 768);
        return r;
    };
    auto loadD = [&](int y) -> Row {
        Row p = rawRow(pred, y), t = rawRow(target, y), r;
        r.a = f4sub(p.a, t.a); r.b = f4sub(p.b, t.b);
        r.c = f4sub(p.c, t.c); r.d = f4sub(p.d, t.d);
        return r;
    };

    float lsum = 0.f, msum = 0.f;

    auto grp = [&](float4 u, float4 c, float4 d, float4 prv, float4 nxt, float4 m) {
        // left neighbor of elem0: rotate-up by 1; lane63 sources prv.w (group to the left)
        const float lsrc = (lane == 63) ? prv.w : c.w;
        const float left = __shfl(lsrc, (lane + 63) & 63, 64);
        // right neighbor of elem3: rotate-down by 1; lane0 sources nxt.x
        const float rsrc = (lane == 0) ? nxt.x : c.x;
        const float right = __shfl(rsrc, (lane + 1) & 63, 64);
        const float l0 = u.x + d.x + left + c.y - 4.f * c.x;
        const float l1 = u.y + d.y + c.x  + c.z - 4.f * c.y;
        const float l2 = u.z + d.z + c.y  + c.w - 4.f * c.z;
        const float l3 = u.w + d.w + c.z  + right - 4.f * c.w;
        lsum += fabsf(l0) * m.x + fabsf(l1) * m.y + fabsf(l2) * m.z + fabsf(l3) * m.w;
        msum += m.x + m.y + m.z + m.w;
    };

    auto stencilRow = [&](const Row& u, const Row& ce, const Row& dn, const Row& m) {
        grp(u.a, ce.a, dn.a, f4z(), ce.b, m.a);   // col 0 pad on the far left
        grp(u.b, ce.b, dn.b, ce.a, ce.c, m.b);
        grp(u.c, ce.c, dn.c, ce.b, ce.d, m.c);
        grp(u.d, ce.d, dn.d, ce.c, f4z(), m.d);   // col 1023 pad on the far right
    };

    Row dP = loadD(wy0 - 1);
    Row dC = loadD(wy0);
    #pragma unroll
    for (int r = 0; r < WROWS; ++r) {
        const int y = wy0 + r;
        const Row m  = rawRow(mask, y);
        const Row dN = loadD(y + 1);
        stencilRow(dP, dC, dN, m);
        dP = dC; dC = dN;
    }

    // ---- Block reduction ----
    for (int off = 32; off > 0; off >>= 1) {
        lsum += __shfl_down(lsum, off, 64);
        msum += __shfl_down(msum, off, 64);
    }
    __shared__ float wls[NT / 64], wms[NT / 64];
    __shared__ unsigned int s_ticket;
    if (lane == 0) { wls[wv] = lsum; wms[wv] = msum; }
    __syncthreads();
    if (tid == 0) {
        float L = 0.f, Mm = 0.f;
        #pragma unroll
        for (int w = 0; w < NT / 64; ++w) { L += wls[w]; Mm += wms[w]; }
        __hip_atomic_store(&partial[2 * (size_t)wid],     L,  __ATOMIC_RELAXED, __HIP_MEMORY_SCOPE_AGENT);
        __hip_atomic_store(&partial[2 * (size_t)wid + 1], Mm, __ATOMIC_RELAXED, __HIP_MEMORY_SCOPE_AGENT);
        __threadfence();
        s_ticket = atomicAdd(counter, 1u);
    }
    __syncthreads();

    // ---- Last block reduces all partials (deterministic order) ----
    if (s_ticket == (unsigned int)(nblocks - 1)) {
        __threadfence();
        float L = 0.f, Mm = 0.f;
        for (int i = tid; i < nblocks; i += NT) {
            L  += __hip_atomic_load(&partial[2 * (size_t)i],     __ATOMIC_RELAXED, __HIP_MEMORY_SCOPE_AGENT);
            Mm += __hip_atomic_load(&partial[2 * (size_t)i + 1], __ATOMIC_RELAXED, __HIP_MEMORY_SCOPE_AGENT);
        }
        for (int off = 32; off > 0; off >>= 1) {
            L  += __shfl_down(L, off, 64);
            Mm += __shfl_down(Mm, off, 64);
        }
        if (lane == 0) { wls[wv] = L; wms[wv] = Mm; }
        __syncthreads();
        if (tid == 0) {
            float LL = 0.f, MM = 0.f;
            #pragma unroll
            for (int w = 0; w < NT / 64; ++w) { LL += wls[w]; MM += wms[w]; }
            out[0] = LL / (MM + 1e-8f);
        }
    }
}

extern "C" void kernel_launch(void* const* d_in, const int* in_sizes, int n_in,
                              void* d_out, int out_size, void* d_ws, size_t ws_size,
                              hipStream_t stream) {
    const float* pred   = (const float*)d_in[0];
    const float* target = (const float*)d_in[1];
    const float* mask   = (const float*)d_in[2];
    float* out = (float*)d_out;

    const int H = IMG_H;
    const int B = in_sizes[0] / (IMG_H * IMG_W);
    const int nblocks = B * (H / (4 * WROWS));        // 16 * 64 = 1024

    float* partial = (float*)d_ws;
    unsigned int* counter = (unsigned int*)((char*)d_ws + 16384);

    hipMemsetAsync(counter, 0, sizeof(unsigned int), stream);
    curv_kernel<<<nblocks, NT, 0, stream>>>(pred, target, mask, partial, counter, out, H, nblocks);
}

// Round 6
// 66.065 us; speedup vs baseline: 2.6735x; 2.6735x over previous
//
#include <hip/hip_runtime.h>

// CurvatureLoss: out = sum(|lap(pred) - lap(target)| * mask) / (sum(mask) + 1e-8)
// lap = 3x3 Laplacian [[0,1,0],[1,-4,1],[0,1,0]], zero ("SAME") padding.
// Linearity: lap(pred)-lap(target) == lap(pred-target).
//
// R5: register-rolling vertical window (named float4s ONLY -- R2/R4 lesson:
// any arrayed per-thread state goes to scratch) + horizontal neighbor exchange
// through a tiny parity-double-buffered LDS array (stride-1, conflict-free,
// ONE barrier/row). This removes R1/R3's divergent per-row edge loads (which
// exposed full memory latency each row) and R0's 2-barriers + bank-conflicted
// bulk LDS. ROWS=16 strips (1.125x halo), fused last-block final reduction,
// XCD-chunked swizzle. Parity write(r&1)->barrier->read(r&1) is race-free:
// a wave can only rewrite buffer p after passing the NEXT barrier, which
// requires all waves to have finished reading buffer p.

static constexpr int IMG_W = 1024;
static constexpr int IMG_H = 1024;
static constexpr int ROWS  = 16;     // output rows per block
static constexpr int NT    = 256;    // 4 cols/thread at W=1024
static constexpr int NXCD  = 8;

__global__ __launch_bounds__(NT) void curv_kernel(
    const float* __restrict__ pred,
    const float* __restrict__ target,
    const float* __restrict__ mask,
    float* __restrict__ partial,        // [2 * nblocks] in d_ws
    unsigned int* __restrict__ counter, // zeroed via hipMemsetAsync each launch
    float* __restrict__ out,
    int H, int nblocks)
{
    // XCD-chunked swizzle: adjacent strips (sharing halo rows) on one XCD's L2.
    const int bid = blockIdx.x;
    const int cpx = nblocks / NXCD;
    const int wid = (bid % NXCD) * cpx + bid / NXCD;

    const int tid  = threadIdx.x;
    const int lane = tid & 63;
    const int bpi  = H / ROWS;
    const int img  = wid / bpi;
    const int y0   = (wid % bpi) * ROWS;
    const size_t imgOff = (size_t)img * H * IMG_W;
    const int x4 = tid * 4;

    __shared__ float sx[2][NT];   // each thread's d_cur.x (col x4)
    __shared__ float sw[2][NT];   // each thread's d_cur.w (col x4+3)

    auto loadD = [&](int y) -> float4 {   // d = pred - target, zero-padded rows
        if (y < 0 || y >= H) return make_float4(0.f, 0.f, 0.f, 0.f);
        const size_t o = imgOff + (size_t)y * IMG_W + x4;
        const float4 p = *reinterpret_cast<const float4*>(pred + o);
        const float4 t = *reinterpret_cast<const float4*>(target + o);
        return make_float4(p.x - t.x, p.y - t.y, p.z - t.z, p.w - t.w);
    };

    float4 d_prev = loadD(y0 - 1);
    float4 d_cur  = loadD(y0);

    float lsum = 0.f, msum = 0.f;

    #pragma unroll 2
    for (int r = 0; r < ROWS; ++r) {
        const int y = y0 + r;
        const int p = r & 1;

        // Publish this row's horizontal boundary values (stride-1, no conflicts).
        sx[p][tid] = d_cur.x;
        sw[p][tid] = d_cur.w;

        // Issue next-row loads BEFORE the barrier -> latency hides under it.
        const float4 d_next = loadD(y + 1);
        const float4 m = *reinterpret_cast<const float4*>(
            mask + imgOff + (size_t)y * IMG_W + x4);

        __syncthreads();

        const float left  = (tid == 0)      ? 0.f : sw[p][tid - 1];
        const float right = (tid == NT - 1) ? 0.f : sx[p][tid + 1];

        const float l0 = d_prev.x + d_next.x + left    + d_cur.y - 4.f * d_cur.x;
        const float l1 = d_prev.y + d_next.y + d_cur.x + d_cur.z - 4.f * d_cur.y;
        const float l2 = d_prev.z + d_next.z + d_cur.y + d_cur.w - 4.f * d_cur.z;
        const float l3 = d_prev.w + d_next.w + d_cur.z + right   - 4.f * d_cur.w;

        lsum += fabsf(l0) * m.x + fabsf(l1) * m.y + fabsf(l2) * m.z + fabsf(l3) * m.w;
        msum += m.x + m.y + m.z + m.w;

        d_prev = d_cur;
        d_cur  = d_next;
    }

    // ---- Block reduction ----
    for (int off = 32; off > 0; off >>= 1) {
        lsum += __shfl_down(lsum, off, 64);
        msum += __shfl_down(msum, off, 64);
    }
    __shared__ float wls[NT / 64], wms[NT / 64];
    __shared__ unsigned int s_ticket;
    const int wave = tid >> 6;
    if (lane == 0) { wls[wave] = lsum; wms[wave] = msum; }
    __syncthreads();
    if (tid == 0) {
        float L = 0.f, Mm = 0.f;
        #pragma unroll
        for (int w = 0; w < NT / 64; ++w) { L += wls[w]; Mm += wms[w]; }
        __hip_atomic_store(&partial[2 * (size_t)wid],     L,  __ATOMIC_RELAXED, __HIP_MEMORY_SCOPE_AGENT);
        __hip_atomic_store(&partial[2 * (size_t)wid + 1], Mm, __ATOMIC_RELAXED, __HIP_MEMORY_SCOPE_AGENT);
        __threadfence();
        s_ticket = atomicAdd(counter, 1u);
    }
    __syncthreads();

    // ---- Last block reduces all partials (deterministic order) ----
    if (s_ticket == (unsigned int)(nblocks - 1)) {
        __threadfence();
        float L = 0.f, Mm = 0.f;
        for (int i = tid; i < nblocks; i += NT) {
            L  += __hip_atomic_load(&partial[2 * (size_t)i],     __ATOMIC_RELAXED, __HIP_MEMORY_SCOPE_AGENT);
            Mm += __hip_atomic_load(&partial[2 * (size_t)i + 1], __ATOMIC_RELAXED, __HIP_MEMORY_SCOPE_AGENT);
        }
        for (int off = 32; off > 0; off >>= 1) {
            L  += __shfl_down(L, off, 64);
            Mm += __shfl_down(Mm, off, 64);
        }
        if (lane == 0) { wls[wave] = L; wms[wave] = Mm; }
        __syncthreads();
        if (tid == 0) {
            float LL = 0.f, MM = 0.f;
            #pragma unroll
            for (int w = 0; w < NT / 64; ++w) { LL += wls[w]; MM += wms[w]; }
            out[0] = LL / (MM + 1e-8f);
        }
    }
}

extern "C" void kernel_launch(void* const* d_in, const int* in_sizes, int n_in,
                              void* d_out, int out_size, void* d_ws, size_t ws_size,
                              hipStream_t stream) {
    const float* pred   = (const float*)d_in[0];
    const float* target = (const float*)d_in[1];
    const float* mask   = (const float*)d_in[2];
    float* out = (float*)d_out;

    const int H = IMG_H;
    const int B = in_sizes[0] / (IMG_H * IMG_W);
    const int nblocks = B * (H / ROWS);        // 16 * 64 = 1024

    float* partial = (float*)d_ws;
    unsigned int* counter = (unsigned int*)((char*)d_ws + 16384);

    hipMemsetAsync(counter, 0, sizeof(unsigned int), stream);
    curv_kernel<<<nblocks, NT, 0, stream>>>(pred, target, mask, partial, counter, out, H, nblocks);
}